// Round 8
// baseline (403.934 us; speedup 1.0000x reference)
//
#include <hip/hip_runtime.h>
#include <math.h>

// B=batch, S=state_dim, D=image channels, N=spatial positions
#define BB 128
#define SS 1024
#define DD 512
#define NN 784
#define NQ 196      // float4 slots per row (784/4)
#define CH 14       // n-chunks per batch (flash-style local softmax)
#define CSL 14      // float4 slots per chunk (14*4 = 56 positions)

__device__ __forceinline__ float wave_reduce_sum(float x) {
#pragma unroll
  for (int m = 32; m > 0; m >>= 1) x += __shfl_xor(x, m, 64);
  return x;
}
__device__ __forceinline__ float wave_reduce_max(float x) {
#pragma unroll
  for (int m = 32; m > 0; m >>= 1) x = fmaxf(x, __shfl_xor(x, m, 64));
  return x;
}

// K1: v[k] = sum_j Wa[j] * Wc[j, k],  k in [0, 2D).  v pre-zeroed by memsetAsync.
__global__ void k1_v(const float* __restrict__ Wa, const float* __restrict__ Wc,
                     float* __restrict__ v) {
  int k = blockIdx.x * 256 + threadIdx.x;
  int j0 = blockIdx.y * 32;
  float acc = 0.f;
#pragma unroll
  for (int j = 0; j < 32; ++j)
    acc += Wa[j0 + j] * Wc[(size_t)(j0 + j) * (2 * DD) + k];
  atomicAdd(&v[k], acc);
}

// K2: w[b,d] = (in_state[b,:]·Wq[d,:] + bq[d]) * v[d] + v[D+d]
__global__ void k2_w(const float* __restrict__ in_state, const float* __restrict__ Wq,
                     const float* __restrict__ bq, const float* __restrict__ v,
                     float* __restrict__ w) {
  __shared__ float st[SS];
  int b = blockIdx.y;
  int t = threadIdx.x, lane = t & 63, wv = t >> 6;
  ((float4*)st)[t] = ((const float4*)(in_state + (size_t)b * SS))[t];
  __syncthreads();
  const float4* st4 = (const float4*)st;
  float4 s0 = st4[lane], s1 = st4[lane + 64], s2 = st4[lane + 128], s3 = st4[lane + 192];
  int d0 = blockIdx.x * 32 + wv * 8;
  float acc[8];
#pragma unroll
  for (int r = 0; r < 8; ++r) {
    const float4* q4 = (const float4*)(Wq + (size_t)(d0 + r) * SS);
    float4 a0 = q4[lane], a1 = q4[lane + 64], a2 = q4[lane + 128], a3 = q4[lane + 192];
    acc[r] = a0.x * s0.x + a0.y * s0.y + a0.z * s0.z + a0.w * s0.w
           + a1.x * s1.x + a1.y * s1.y + a1.z * s1.z + a1.w * s1.w
           + a2.x * s2.x + a2.y * s2.y + a2.z * s2.z + a2.w * s2.w
           + a3.x * s3.x + a3.y * s3.y + a3.z * s3.z + a3.w * s3.w;
  }
#pragma unroll
  for (int r = 0; r < 8; ++r) acc[r] = wave_reduce_sum(acc[r]);
  if (lane == 0) {
#pragma unroll
    for (int r = 0; r < 8; ++r) {
      int d = d0 + r;
      w[(size_t)b * DD + d] = (acc[r] + bq[d]) * v[d] + v[DD + d];
    }
  }
}

// K3: SINGLE image pass. Block (c, b) owns n-slots [c*14, c*14+14) of all 512
// rows, held in LDS (115 KB -> 1 block/CU, 8 waves). Steps:
//  load: cooperative coalesced walk f = t + k*512 (r=f/14, j=f%14), 14
//        float4/thread issued back-to-back (112 KB in flight per CU).
//  logits: thread t computes w[t]*xs[t][j]; per-wave shuffle-reduce each of
//        the 14 float4 slots; cross-wave LDS tree -> l[56].
//  local softmax: m_c, Z_c, u[j] (redundant-uniform per thread).
//  pool: P_c[d=t] = sum_j dot(u[j], xs[t][j]) — private dot on own LDS row.
// Emits P_part[b][c][512] + (m_c, Z_c); k5 flash-combines the 14 chunks.
__global__ __launch_bounds__(512, 2) void k3_chunk(
    const float* __restrict__ image, const float* __restrict__ w,
    float* __restrict__ P_part, float* __restrict__ mZ_part) {
  __shared__ float4 xs[DD][CSL + 1];   // +1 pad: 512*15*16 = 122880 B
  __shared__ float4 lred[8][CSL];      // per-wave logit partials
  int b = blockIdx.y, c = blockIdx.x;
  int t = threadIdx.x, lane = t & 63, wv = t >> 6;
  const char* base = (const char*)image + (size_t)b * DD * (NN * 4) + c * (CSL * 16);
  // ---- cooperative coalesced load: 512 rows x 14 float4 ----
#pragma unroll
  for (int k = 0; k < CSL; ++k) {
    int f = t + k * 512;
    int r = f / CSL, j = f % CSL;
    float4 x = *(const float4*)(base + (size_t)r * (NN * 4) + j * 16);
    xs[r][j] = x;
  }
  float wt = w[(size_t)b * DD + t];
  __syncthreads();
  // ---- chunk logits: reduce w[t]*xs[t][j] over all 512 threads ----
#pragma unroll
  for (int j = 0; j < CSL; ++j) {
    float4 x = xs[t][j];
    float4 s;
    s.x = wave_reduce_sum(wt * x.x);
    s.y = wave_reduce_sum(wt * x.y);
    s.z = wave_reduce_sum(wt * x.z);
    s.w = wave_reduce_sum(wt * x.w);
    if (lane == 0) lred[wv][j] = s;
  }
  __syncthreads();
  // ---- local softmax over 56 positions (uniform per thread) ----
  float4 l[CSL];
#pragma unroll
  for (int j = 0; j < CSL; ++j) {
    float4 s = lred[0][j];
#pragma unroll
    for (int v8 = 1; v8 < 8; ++v8) {
      float4 p = lred[v8][j];
      s.x += p.x; s.y += p.y; s.z += p.z; s.w += p.w;
    }
    l[j] = s;
  }
  float m = -1e30f;
#pragma unroll
  for (int j = 0; j < CSL; ++j)
    m = fmaxf(m, fmaxf(fmaxf(l[j].x, l[j].y), fmaxf(l[j].z, l[j].w)));
  float Z = 0.f;
#pragma unroll
  for (int j = 0; j < CSL; ++j) {
    l[j].x = __expf(l[j].x - m); l[j].y = __expf(l[j].y - m);
    l[j].z = __expf(l[j].z - m); l[j].w = __expf(l[j].w - m);
    Z += l[j].x + l[j].y + l[j].z + l[j].w;
  }
  // ---- pool: private dot of u with own LDS row ----
  float acc = 0.f;
#pragma unroll
  for (int j = 0; j < CSL; ++j) {
    float4 x = xs[t][j];
    acc += l[j].x * x.x + l[j].y * x.y + l[j].z * x.z + l[j].w * x.w;
  }
  P_part[((size_t)b * CH + c) * DD + t] = acc;
  if (t == 0) {
    mZ_part[((size_t)b * CH + c) * 2 + 0] = m;
    mZ_part[((size_t)b * CH + c) * 2 + 1] = Z;
  }
}

// K5: flash-combine 14 chunk partials -> pooled[b,d]. grid B, block 128.
__global__ void k5_combine(const float* __restrict__ P_part, const float* __restrict__ mZ_part,
                           float* __restrict__ pooled) {
  int b = blockIdx.x, t = threadIdx.x;
  float mc[CH], Zc[CH];
  float M = -1e30f;
#pragma unroll
  for (int c = 0; c < CH; ++c) {
    mc[c] = mZ_part[((size_t)b * CH + c) * 2 + 0];
    Zc[c] = mZ_part[((size_t)b * CH + c) * 2 + 1];
    M = fmaxf(M, mc[c]);
  }
  float Z = 0.f, al[CH];
#pragma unroll
  for (int c = 0; c < CH; ++c) { al[c] = __expf(mc[c] - M); Z += al[c] * Zc[c]; }
  float inv = 1.0f / Z;
  float4 s = {0, 0, 0, 0};
#pragma unroll
  for (int c = 0; c < CH; ++c) {
    float4 p = ((const float4*)P_part)[((size_t)b * CH + c) * 128 + t];
    s.x += al[c] * p.x; s.y += al[c] * p.y; s.z += al[c] * p.z; s.w += al[c] * p.w;
  }
  s.x *= inv; s.y *= inv; s.z *= inv; s.w *= inv;
  ((float4*)pooled)[(size_t)b * 128 + t] = s;
}

// K6: out[b,s] = pooled[b,:]·Wo[s,:] + bo[s]
__global__ void k6_out(const float* __restrict__ pooled, const float* __restrict__ Wo,
                       const float* __restrict__ bo, float* __restrict__ out) {
  __shared__ float p_s[DD];
  int b = blockIdx.y, t = threadIdx.x, lane = t & 63, wv = t >> 6;
  ((float2*)p_s)[t] = ((const float2*)(pooled + (size_t)b * DD))[t];
  __syncthreads();
  const float4* p4 = (const float4*)p_s;
  float4 p0 = p4[lane], p1 = p4[lane + 64];
  int s0 = blockIdx.x * 32 + wv * 8;
  float acc[8];
#pragma unroll
  for (int r = 0; r < 8; ++r) {
    const float4* wo4 = (const float4*)(Wo + (size_t)(s0 + r) * DD);
    float4 x0 = wo4[lane], x1 = wo4[lane + 64];
    acc[r] = x0.x * p0.x + x0.y * p0.y + x0.z * p0.z + x0.w * p0.w
           + x1.x * p1.x + x1.y * p1.y + x1.z * p1.z + x1.w * p1.w;
  }
#pragma unroll
  for (int r = 0; r < 8; ++r) acc[r] = wave_reduce_sum(acc[r]);
  if (lane == 0) {
#pragma unroll
    for (int r = 0; r < 8; ++r) out[(size_t)b * SS + s0 + r] = acc[r] + bo[s0 + r];
  }
}

extern "C" void kernel_launch(void* const* d_in, const int* in_sizes, int n_in,
                              void* d_out, int out_size, void* d_ws, size_t ws_size,
                              hipStream_t stream) {
  const float* in_state = (const float*)d_in[0];
  const float* image    = (const float*)d_in[1];
  const float* Wq       = (const float*)d_in[2];
  const float* bq       = (const float*)d_in[3];
  const float* Wc       = (const float*)d_in[4];
  const float* Wa       = (const float*)d_in[6];
  const float* Wo       = (const float*)d_in[8];
  const float* bo       = (const float*)d_in[9];
  float* out = (float*)d_out;

  // workspace layout (floats): ~4.2 MB total
  float* ws      = (float*)d_ws;
  float* v       = ws;                                // 2D          = 1024
  float* w       = v + 2 * DD;                        // B*D         = 65536
  float* P_part  = w + (size_t)BB * DD;               // B*CH*D      = 917504
  float* mZ_part = P_part + (size_t)BB * CH * DD;     // B*CH*2      = 3584
  float* pooled  = mZ_part + (size_t)BB * CH * 2;     // B*D         = 65536

  hipMemsetAsync(v, 0, 2 * DD * sizeof(float), stream);
  k1_v<<<dim3(4, 16), 256, 0, stream>>>(Wa, Wc, v);
  k2_w<<<dim3(16, BB), 256, 0, stream>>>(in_state, Wq, bq, v, w);
  k3_chunk<<<dim3(CH, BB), 512, 0, stream>>>(image, w, P_part, mZ_part);
  k5_combine<<<BB, 128, 0, stream>>>(P_part, mZ_part, pooled);
  k6_out<<<dim3(32, BB), 256, 0, stream>>>(pooled, Wo, bo, out);
}